// Round 4
// baseline (485.269 us; speedup 1.0000x reference)
//
#include <hip/hip_runtime.h>
#include <hip/hip_bf16.h>
#include <math.h>

#define B_   2
#define S_   2048
#define HID  2048
#define NH   16
#define HD   128

typedef __bf16 bf16_t;
typedef __bf16 bf16x4 __attribute__((ext_vector_type(4)));
typedef __bf16 bf16x8 __attribute__((ext_vector_type(8)));
typedef float  f32x4  __attribute__((ext_vector_type(4)));

__device__ __forceinline__ f32x4 mfma16(bf16x8 a, bf16x8 b, f32x4 c) {
    return __builtin_amdgcn_mfma_f32_16x16x32_bf16(a, b, c, 0, 0, 0);
}

__device__ __forceinline__ void gl2lds16(const void* g, void* l) {
    __builtin_amdgcn_global_load_lds((__attribute__((address_space(1))) void*)(g),
                                     (__attribute__((address_space(3))) void*)(l),
                                     16, 0, 0);
}

// ---------------------------------------------------------------------------
// fp32 -> bf16 conversion of hs + 4 weights (float4 in, bf16x4 out).
// float4 counts (cum): hs 2097152 | Wq 1048576 | Wk 65536 | Wv 65536 | Wo 1048576
// ---------------------------------------------------------------------------
__global__ void convert_bf16(const float* __restrict__ s0, const float* __restrict__ s1,
                             const float* __restrict__ s2, const float* __restrict__ s3,
                             const float* __restrict__ s4,
                             bf16_t* __restrict__ d0, bf16_t* __restrict__ d1,
                             bf16_t* __restrict__ d2, bf16_t* __restrict__ d3,
                             bf16_t* __restrict__ d4)
{
    const size_t stride = (size_t)gridDim.x * blockDim.x;
    for (size_t i = (size_t)blockIdx.x * blockDim.x + threadIdx.x; i < 4325376; i += stride) {
        const float* s; bf16_t* d; size_t off;
        if (i < 2097152)      { s = s0; d = d0; off = i; }
        else if (i < 3145728) { s = s1; d = d1; off = i - 2097152; }
        else if (i < 3211264) { s = s2; d = d2; off = i - 3145728; }
        else if (i < 3276800) { s = s3; d = d3; off = i - 3211264; }
        else                  { s = s4; d = d4; off = i - 3276800; }
        float4 v = ((const float4*)s)[off];
        bf16x4 o;
        o[0] = (bf16_t)v.x; o[1] = (bf16_t)v.y; o[2] = (bf16_t)v.z; o[3] = (bf16_t)v.w;
        ((bf16x4*)d)[off] = o;
    }
}

// ---------------------------------------------------------------------------
// broadcast compact bf16 K/V [b][s][128] -> fp32 key/value_states [b][16][s][128].
// Per region: 8388608 floats = 2097152 float4. Total i < 4194304.
// e = ((b*16+h)*2048+s)*128+d ; b=e>>22, s=(e>>7)&2047, d=e&127.
// ---------------------------------------------------------------------------
__global__ void broadcast_kv(const bf16_t* __restrict__ k_ws, const bf16_t* __restrict__ v_ws,
                             float* __restrict__ keyo, float* __restrict__ valo)
{
    const size_t stride = (size_t)gridDim.x * blockDim.x;
    for (size_t i = (size_t)blockIdx.x * blockDim.x + threadIdx.x; i < 4194304; i += stride) {
        int which = i >= 2097152;
        size_t f = which ? i - 2097152 : i;
        size_t e = f * 4;                         // < 8388608
        int d = (int)(e & 127);
        size_t s = (e >> 7) & 2047;
        size_t b = e >> 22;                       // 0 or 1 (h irrelevant for src)
        const bf16_t* src = (which ? v_ws : k_ws) + (b * S_ + s) * HD + d;
        bf16x4 kv = *(const bf16x4*)src;
        float4 o;
        o.x = (float)kv[0]; o.y = (float)kv[1]; o.z = (float)kv[2]; o.w = (float)kv[3];
        *(float4*)((which ? valo : keyo) + e) = o;
    }
}

// ---------------------------------------------------------------------------
// NT GEMM, 128x128 tile, BK=32, 4 waves (2x2 of 64x64), mfma 16x16x32 bf16.
// MODE 0: C = Xb @ [Wq;Wk;Wv]b^T (N=2304): bn<16 -> qb bf16; bn==16 -> k_ws;
//         bn==17 -> v_ws + vt_ws (transposed).
// MODE 1: C = O @ Wo^T -> fp32 out.
// ---------------------------------------------------------------------------
template <int MODE>
__global__ __launch_bounds__(256, 2)
void gemm_nt(const bf16_t* __restrict__ A,  const bf16_t* __restrict__ B0,
             const bf16_t* __restrict__ B1, const bf16_t* __restrict__ B2,
             bf16_t* __restrict__ q_ws, bf16_t* __restrict__ k_ws,
             bf16_t* __restrict__ v_ws, bf16_t* __restrict__ vt_ws,
             float* __restrict__ outf)
{
    __shared__ __align__(16) ushort sA[128 * 32];
    __shared__ __align__(16) ushort sB[128 * 32];

    const int tid  = threadIdx.x;
    const int lane = tid & 63;
    const int wave = tid >> 6;
    const int quad = lane >> 4;
    const int l16  = lane & 15;
    const int bn = blockIdx.x, bm = blockIdx.y;
    const int wm = (wave & 1) * 64;
    const int wn = (wave >> 1) * 64;

    const bf16_t* Bbase;
    if (MODE == 0) Bbase = (bn < 16) ? (B0 + (size_t)bn * 128 * HID) : (bn == 16 ? B1 : B2);
    else           Bbase = B0 + (size_t)bn * 128 * HID;
    const bf16_t* Abase = A + (size_t)bm * 128 * HID;

    const int c0 = tid, c1 = tid + 256;
    const int r0 = c0 >> 2, o0 = (c0 & 3) * 8;
    const int r1 = c1 >> 2, o1 = (c1 & 3) * 8;

    f32x4 acc[4][4] = {};

    for (int kt = 0; kt < HID / 32; ++kt) {
        const int ko = kt * 32;
        gl2lds16(Abase + (size_t)r0 * HID + ko + o0, sA + c0 * 8);
        gl2lds16(Abase + (size_t)r1 * HID + ko + o1, sA + c1 * 8);
        gl2lds16(Bbase + (size_t)r0 * HID + ko + o0, sB + c0 * 8);
        gl2lds16(Bbase + (size_t)r1 * HID + ko + o1, sB + c1 * 8);
        __syncthreads();

        bf16x8 af[4], bfr[4];
        for (int mt = 0; mt < 4; ++mt)
            af[mt] = *(const bf16x8*)(sA + (wm + mt * 16 + l16) * 32 + quad * 8);
        for (int nt = 0; nt < 4; ++nt)
            bfr[nt] = *(const bf16x8*)(sB + (wn + nt * 16 + l16) * 32 + quad * 8);
        for (int mt = 0; mt < 4; ++mt)
            for (int nt = 0; nt < 4; ++nt)
                acc[mt][nt] = mfma16(af[mt], bfr[nt], acc[mt][nt]);
        __syncthreads();
    }

    // epilogue: C/D layout col=lane&15, row=(lane>>4)*4+reg  [verified m89/m91]
    for (int mt = 0; mt < 4; ++mt) {
        for (int nt = 0; nt < 4; ++nt) {
            for (int j = 0; j < 4; ++j) {
                float v = acc[mt][nt][j];
                int row = bm * 128 + wm + mt * 16 + quad * 4 + j;   // token
                int col = wn + nt * 16 + l16;                        // within-block n
                if (MODE == 1) {
                    outf[(size_t)row * HID + bn * 128 + col] = v;
                } else {
                    bf16_t bv = (bf16_t)v;
                    if (bn < 16) {
                        q_ws[(size_t)row * HID + bn * 128 + col] = bv;
                    } else {
                        int b = row >> 11, s = row & 2047, d = col;
                        if (bn == 16) {
                            k_ws[((size_t)b * S_ + s) * HD + d] = bv;
                        } else {
                            v_ws[((size_t)b * S_ + s) * HD + d] = bv;
                            vt_ws[((size_t)b * HD + d) * S_ + s] = bv;
                        }
                    }
                }
            }
        }
    }
}

// ---------------------------------------------------------------------------
// Flash-style MQA attention. Block = (q-tile of 128 rows) x (b,h).
// 4 waves; wave w owns q-rows w*32..w*32+31. K-tiles of 64 keys, 32 iters.
// LDS 54.5 KB: sK [64][136], sV(=V^T tile) [128][72], sP [4][32][72], mask.
// ---------------------------------------------------------------------------
#define SK_OFF 0
#define SV_OFF 8704
#define SP_OFF 17920
#define SM_OFF 27136   // floats from here

__global__ __launch_bounds__(256, 1)
void attn_kernel(const bf16_t* __restrict__ Qw, const bf16_t* __restrict__ Kc,
                 const bf16_t* __restrict__ Vt, const float* __restrict__ mask,
                 bf16_t* __restrict__ Ow)
{
    __shared__ __align__(16) ushort smem[27264];
    float* sMask = (float*)&smem[SM_OFF];

    const int tid  = threadIdx.x;
    const int lane = tid & 63;
    const int wave = tid >> 6;
    const int quad = lane >> 4;
    const int l16  = lane & 15;
    const int qt = blockIdx.x;           // 0..15
    const int bh = blockIdx.y;           // 0..31
    const int b = bh >> 4, h = bh & 15;

    // ---- stage Q tile [128 rows][128 d] into smem[0..17408) (overlays K/V) ----
    {
        const bf16_t* qg = Qw + ((size_t)(b * S_ + qt * 128)) * HID + h * HD;
        for (int i = 0; i < 8; ++i) {
            int c = tid + i * 256;                  // 0..2047
            int row = c >> 4, col = (c & 15) * 8;
            *(uint4*)(&smem[row * 136 + col]) = *(const uint4*)(qg + (size_t)row * HID + col);
        }
    }
    __syncthreads();

    bf16x8 qf[2][4];
    for (int mt = 0; mt < 2; ++mt)
        for (int kk = 0; kk < 4; ++kk)
            qf[mt][kk] = *(const bf16x8*)(&smem[(wave * 32 + mt * 16 + l16) * 136 + kk * 32 + quad * 8]);

    f32x4 oa[2][8] = {};
    float mrow[2][4], lrow[2][4];
    for (int mt = 0; mt < 2; ++mt)
        for (int j = 0; j < 4; ++j) { mrow[mt][j] = -INFINITY; lrow[mt][j] = 0.f; }

    const float scale = 0.08838834764831845f;           // 1/sqrt(128)
    const float NEGF  = -3.4028234663852886e38f;        // float32 finfo.min

    const bf16_t* kg = Kc + (size_t)b * S_ * HD;
    const bf16_t* vg = Vt + (size_t)b * HD * S_;

    for (int kt = 0; kt < S_ / 64; ++kt) {
        __syncthreads();   // prior compute done (also protects Q overlay at kt=0)
        for (int i = 0; i < 4; ++i) {
            int c = tid + i * 256;                       // 0..1023
            int kr = c >> 4, kc = (c & 15) * 8;          // K: [64][128]
            *(uint4*)(&smem[SK_OFF + kr * 136 + kc]) =
                *(const uint4*)(kg + (size_t)(kt * 64 + kr) * HD + kc);
            int vr = c >> 3, vc = (c & 7) * 8;           // V^T: [128][64]
            *(uint4*)(&smem[SV_OFF + vr * 72 + vc]) =
                *(const uint4*)(vg + (size_t)vr * S_ + kt * 64 + vc);
        }
        if (tid < 64) {
            float mv = mask[b * S_ + kt * 64 + tid];
            sMask[tid] = (1.0f - mv) * NEGF;
        }
        __syncthreads();

        // ---- S = (Q K^T) * scale + maskadd ----
        f32x4 sa[2][4];
        for (int nt = 0; nt < 4; ++nt) {
            bf16x8 kf[4];
            for (int kk = 0; kk < 4; ++kk)
                kf[kk] = *(const bf16x8*)(&smem[SK_OFF + (nt * 16 + l16) * 136 + kk * 32 + quad * 8]);
            for (int mt = 0; mt < 2; ++mt) {
                f32x4 a = {};
                for (int kk = 0; kk < 4; ++kk)
                    a = mfma16(qf[mt][kk], kf[kk], a);
                sa[mt][nt] = a;
            }
        }
        for (int mt = 0; mt < 2; ++mt)
            for (int nt = 0; nt < 4; ++nt) {
                float madd = sMask[nt * 16 + l16];
                for (int j = 0; j < 4; ++j)
                    sa[mt][nt][j] = sa[mt][nt][j] * scale + madd;
            }

        // ---- online softmax (rows live in one 16-lane quad) ----
        for (int mt = 0; mt < 2; ++mt) {
            float rm[4];
            for (int j = 0; j < 4; ++j) {
                float m = sa[mt][0][j];
                for (int nt = 1; nt < 4; ++nt) m = fmaxf(m, sa[mt][nt][j]);
                rm[j] = m;
            }
            for (int off = 1; off < 16; off <<= 1)
                for (int j = 0; j < 4; ++j)
                    rm[j] = fmaxf(rm[j], __shfl_xor(rm[j], off));
            float alpha[4];
            for (int j = 0; j < 4; ++j) {
                float mnew = fmaxf(mrow[mt][j], rm[j]);
                alpha[j] = __expf(mrow[mt][j] - mnew);
                mrow[mt][j] = mnew;
                lrow[mt][j] *= alpha[j];
                for (int nt = 0; nt < 8; ++nt) oa[mt][nt][j] *= alpha[j];
            }
            float rs[4] = {0.f, 0.f, 0.f, 0.f};
            bf16_t* sPp = (bf16_t*)&smem[SP_OFF + wave * 2304];
            for (int nt = 0; nt < 4; ++nt)
                for (int j = 0; j < 4; ++j) {
                    float p = __expf(sa[mt][nt][j] - mrow[mt][j]);
                    rs[j] += p;
                    sPp[(mt * 16 + quad * 4 + j) * 72 + nt * 16 + l16] = (bf16_t)p;
                }
            for (int off = 1; off < 16; off <<= 1)
                for (int j = 0; j < 4; ++j) rs[j] += __shfl_xor(rs[j], off);
            for (int j = 0; j < 4; ++j) lrow[mt][j] += rs[j];
        }

        // ---- O += P V  (P via LDS round-trip: C-layout -> A-layout) ----
        bf16x8 pf[2][2];
        for (int mt = 0; mt < 2; ++mt)
            for (int kk = 0; kk < 2; ++kk)
                pf[mt][kk] = *(const bf16x8*)(&smem[SP_OFF + wave * 2304 + (mt * 16 + l16) * 72 + kk * 32 + quad * 8]);
        for (int nt = 0; nt < 8; ++nt)
            for (int kk = 0; kk < 2; ++kk) {
                bf16x8 vf = *(const bf16x8*)(&smem[SV_OFF + (nt * 16 + l16) * 72 + kk * 32 + quad * 8]);
                for (int mt = 0; mt < 2; ++mt)
                    oa[mt][nt] = mfma16(pf[mt][kk], vf, oa[mt][nt]);
            }
    }

    // ---- epilogue: O /= l, write [b,s,h*128+d] ----
    for (int mt = 0; mt < 2; ++mt)
        for (int j = 0; j < 4; ++j) {
            float inv = 1.0f / lrow[mt][j];
            int s = qt * 128 + wave * 32 + mt * 16 + quad * 4 + j;
            for (int nt = 0; nt < 8; ++nt) {
                int d = nt * 16 + l16;
                Ow[((size_t)(b * S_ + s)) * HID + h * HD + d] = (bf16_t)(oa[mt][nt][j] * inv);
            }
        }
}

// ---------------------------------------------------------------------------
// Scratch overlay inside d_out (all regions phase-disjoint):
//   O1 = out[0 : 8388608)          : wqb/wkb/wvb bf16 (9 MB)   -> final out (gemm1)
//   O2 = out[8388608 : 16777216)   : qb bf16 16.8MB | wob bf16 8MB -> final key (bcast)
//   O3 = out[16777216 : 25165824)  : hsb bf16 16.8MB, then o_ws (alias) -> final value (bcast)
// d_ws: k_ws/v_ws/vt_ws bf16 = 3 MB only.
// Order: convert -> gemm0 -> attn -> gemm1 -> broadcast_kv (last).
// ---------------------------------------------------------------------------
extern "C" void kernel_launch(void* const* d_in, const int* in_sizes, int n_in,
                              void* d_out, int out_size, void* d_ws, size_t ws_size,
                              hipStream_t stream) {
    const float* hs   = (const float*)d_in[0];
    const float* mask = (const float*)d_in[1];
    const float* Wq   = (const float*)d_in[2];
    const float* Wk   = (const float*)d_in[3];
    const float* Wv   = (const float*)d_in[4];
    const float* Wo   = (const float*)d_in[5];
    float* out = (float*)d_out;

    bf16_t* wqb = (bf16_t*)out;                         // O1: 4,194,304 bf16
    bf16_t* wkb = wqb + 4194304;                        //       262,144
    bf16_t* wvb = wkb + 262144;                         //       262,144
    bf16_t* qb  = (bf16_t*)(out + 8388608);             // O2: 8,388,608 bf16
    bf16_t* wob = (bf16_t*)(out + 12582912);            // O2 tail: 4,194,304 bf16
    bf16_t* hsb = (bf16_t*)(out + 16777216);            // O3: 8,388,608 bf16
    bf16_t* o_ws = hsb;                                 // alias (hsb dead after gemm0)

    bf16_t* k_ws  = (bf16_t*)d_ws;                      // 524,288 bf16
    bf16_t* v_ws  = k_ws + 524288;
    bf16_t* vt_ws = v_ws + 524288;                      // total 3 MB

    // 1) fp32 -> bf16 staging
    convert_bf16<<<2048, 256, 0, stream>>>(hs, Wq, Wk, Wv, Wo, hsb, wqb, wkb, wvb, wob);
    // 2) QKV projection: Q->qb (O2), K->k_ws, V->v_ws + vt_ws
    gemm_nt<0><<<dim3(18, 32), 256, 0, stream>>>(hsb, wqb, wkb, wvb, qb, k_ws, v_ws, vt_ws, nullptr);
    // 3) flash MQA attention -> o_ws (O3, overwrites dead hsb)
    attn_kernel<<<dim3(16, 32), 256, 0, stream>>>(qb, k_ws, vt_ws, mask, o_ws);
    // 4) output projection -> fp32 out (O1, overwrites dead wq/wk/wv)
    gemm_nt<1><<<dim3(16, 32), 256, 0, stream>>>(o_ws, wob, nullptr, nullptr, nullptr, nullptr, nullptr, nullptr, out);
    // 5) key/value broadcast -> O2/O3 (overwrites dead qb/wob/o_ws)
    broadcast_kv<<<4096, 256, 0, stream>>>(k_ws, v_ws, out + 8388608, out + 16777216);
}

// Round 5
// 410.181 us; speedup vs baseline: 1.1831x; 1.1831x over previous
//
#include <hip/hip_runtime.h>
#include <hip/hip_bf16.h>
#include <math.h>

#define B_   2
#define S_   2048
#define HID  2048
#define NH   16
#define HD   128

typedef __bf16 bf16_t;
typedef __bf16 bf16x4 __attribute__((ext_vector_type(4)));
typedef __bf16 bf16x8 __attribute__((ext_vector_type(8)));
typedef float  f32x4  __attribute__((ext_vector_type(4)));

__device__ __forceinline__ f32x4 mfma16(bf16x8 a, bf16x8 b, f32x4 c) {
    return __builtin_amdgcn_mfma_f32_16x16x32_bf16(a, b, c, 0, 0, 0);
}

__device__ __forceinline__ void gl2lds16(const void* g, void* l) {
    __builtin_amdgcn_global_load_lds((__attribute__((address_space(1))) void*)(g),
                                     (__attribute__((address_space(3))) void*)(l),
                                     16, 0, 0);
}

// ---------------------------------------------------------------------------
// fp32 -> bf16 conversion of hs + 4 weights (float4 in, bf16x4 out).
// float4 counts (cum): hs 2097152 | Wq 1048576 | Wk 65536 | Wv 65536 | Wo 1048576
// ---------------------------------------------------------------------------
__global__ void convert_bf16(const float* __restrict__ s0, const float* __restrict__ s1,
                             const float* __restrict__ s2, const float* __restrict__ s3,
                             const float* __restrict__ s4,
                             bf16_t* __restrict__ d0, bf16_t* __restrict__ d1,
                             bf16_t* __restrict__ d2, bf16_t* __restrict__ d3,
                             bf16_t* __restrict__ d4)
{
    const size_t stride = (size_t)gridDim.x * blockDim.x;
    for (size_t i = (size_t)blockIdx.x * blockDim.x + threadIdx.x; i < 4325376; i += stride) {
        const float* s; bf16_t* d; size_t off;
        if (i < 2097152)      { s = s0; d = d0; off = i; }
        else if (i < 3145728) { s = s1; d = d1; off = i - 2097152; }
        else if (i < 3211264) { s = s2; d = d2; off = i - 3145728; }
        else if (i < 3276800) { s = s3; d = d3; off = i - 3211264; }
        else                  { s = s4; d = d4; off = i - 3276800; }
        float4 v = ((const float4*)s)[off];
        bf16x4 o;
        o[0] = (bf16_t)v.x; o[1] = (bf16_t)v.y; o[2] = (bf16_t)v.z; o[3] = (bf16_t)v.w;
        ((bf16x4*)d)[off] = o;
    }
}

// ---------------------------------------------------------------------------
// broadcast compact bf16 K/V [b][s][128] -> fp32 key/value_states [b][16][s][128].
// Per region: 8388608 floats = 2097152 float4. Total i < 4194304.
// ---------------------------------------------------------------------------
__global__ void broadcast_kv(const bf16_t* __restrict__ k_ws, const bf16_t* __restrict__ v_ws,
                             float* __restrict__ keyo, float* __restrict__ valo)
{
    const size_t stride = (size_t)gridDim.x * blockDim.x;
    for (size_t i = (size_t)blockIdx.x * blockDim.x + threadIdx.x; i < 4194304; i += stride) {
        int which = i >= 2097152;
        size_t f = which ? i - 2097152 : i;
        size_t e = f * 4;                         // < 8388608
        int d = (int)(e & 127);
        size_t s = (e >> 7) & 2047;
        size_t b = e >> 22;                       // 0 or 1
        const bf16_t* src = (which ? v_ws : k_ws) + (b * S_ + s) * HD + d;
        bf16x4 kv = *(const bf16x4*)src;
        float4 o;
        o.x = (float)kv[0]; o.y = (float)kv[1]; o.z = (float)kv[2]; o.w = (float)kv[3];
        *(float4*)((which ? valo : keyo) + e) = o;
    }
}

// ---------------------------------------------------------------------------
// NT GEMM, 128x128 tile, BK=32, 4 waves (2x2 of 64x64), mfma 16x16x32 bf16.
// MODE 0: C = Xb @ [Wq;Wk;Wv]b^T (N=2304): bn<16 -> qb; bn==16 -> k_ws;
//         bn==17 -> v_ws + vt_ws.   MODE 1: C = O @ Wo^T -> fp32 out.
// ---------------------------------------------------------------------------
template <int MODE>
__global__ __launch_bounds__(256, 2)
void gemm_nt(const bf16_t* __restrict__ A,  const bf16_t* __restrict__ B0,
             const bf16_t* __restrict__ B1, const bf16_t* __restrict__ B2,
             bf16_t* __restrict__ q_ws, bf16_t* __restrict__ k_ws,
             bf16_t* __restrict__ v_ws, bf16_t* __restrict__ vt_ws,
             float* __restrict__ outf)
{
    __shared__ __align__(16) ushort sA[128 * 32];
    __shared__ __align__(16) ushort sB[128 * 32];

    const int tid  = threadIdx.x;
    const int lane = tid & 63;
    const int wave = tid >> 6;
    const int quad = lane >> 4;
    const int l16  = lane & 15;
    const int bn = blockIdx.x, bm = blockIdx.y;
    const int wm = (wave & 1) * 64;
    const int wn = (wave >> 1) * 64;

    const bf16_t* Bbase;
    if (MODE == 0) Bbase = (bn < 16) ? (B0 + (size_t)bn * 128 * HID) : (bn == 16 ? B1 : B2);
    else           Bbase = B0 + (size_t)bn * 128 * HID;
    const bf16_t* Abase = A + (size_t)bm * 128 * HID;

    const int c0 = tid, c1 = tid + 256;
    const int r0 = c0 >> 2, o0 = (c0 & 3) * 8;
    const int r1 = c1 >> 2, o1 = (c1 & 3) * 8;

    f32x4 acc[4][4] = {};

    for (int kt = 0; kt < HID / 32; ++kt) {
        const int ko = kt * 32;
        gl2lds16(Abase + (size_t)r0 * HID + ko + o0, sA + c0 * 8);
        gl2lds16(Abase + (size_t)r1 * HID + ko + o1, sA + c1 * 8);
        gl2lds16(Bbase + (size_t)r0 * HID + ko + o0, sB + c0 * 8);
        gl2lds16(Bbase + (size_t)r1 * HID + ko + o1, sB + c1 * 8);
        __syncthreads();

        bf16x8 af[4], bfr[4];
        for (int mt = 0; mt < 4; ++mt)
            af[mt] = *(const bf16x8*)(sA + (wm + mt * 16 + l16) * 32 + quad * 8);
        for (int nt = 0; nt < 4; ++nt)
            bfr[nt] = *(const bf16x8*)(sB + (wn + nt * 16 + l16) * 32 + quad * 8);
        for (int mt = 0; mt < 4; ++mt)
            for (int nt = 0; nt < 4; ++nt)
                acc[mt][nt] = mfma16(af[mt], bfr[nt], acc[mt][nt]);
        __syncthreads();
    }

    for (int mt = 0; mt < 4; ++mt) {
        for (int nt = 0; nt < 4; ++nt) {
            for (int j = 0; j < 4; ++j) {
                float v = acc[mt][nt][j];
                int row = bm * 128 + wm + mt * 16 + quad * 4 + j;
                int col = wn + nt * 16 + l16;
                if (MODE == 1) {
                    outf[(size_t)row * HID + bn * 128 + col] = v;
                } else {
                    bf16_t bv = (bf16_t)v;
                    if (bn < 16) {
                        q_ws[(size_t)row * HID + bn * 128 + col] = bv;
                    } else {
                        int b = row >> 11, s = row & 2047, d = col;
                        if (bn == 16) {
                            k_ws[((size_t)b * S_ + s) * HD + d] = bv;
                        } else {
                            v_ws[((size_t)b * S_ + s) * HD + d] = bv;
                            vt_ws[((size_t)b * HD + d) * S_ + s] = bv;
                        }
                    }
                }
            }
        }
    }
}

// ---------------------------------------------------------------------------
// Flash-style MQA attention, occupancy-oriented rework.
// Block = 512 threads (8 waves) x (q-tile of 256 rows) x (b,h). Grid (8,32)
// = 256 blocks = exactly 1 per CU. Wave w owns q-rows w*32..w*32+31.
// K-tiles of 64 keys, 32 iters. Q frags loaded global->reg (no Q staging).
// LDS 55.5 KB: region1 = sP [8][32][72] (overlays sK [64][136]), sV [128][72],
// mask. 3 barriers/iter (extra one protects sK-read vs sP-write overlay).
// ---------------------------------------------------------------------------
#define SV_U 18432   // ushort offset of sV
#define SM_U 27648   // ushort offset of mask floats

__global__ __launch_bounds__(512, 2)
void attn_kernel(const bf16_t* __restrict__ Qw, const bf16_t* __restrict__ Kc,
                 const bf16_t* __restrict__ Vt, const float* __restrict__ mask,
                 bf16_t* __restrict__ Ow)
{
    __shared__ __align__(16) ushort smem[27776];
    float* sMask = (float*)&smem[SM_U];

    const int tid  = threadIdx.x;
    const int lane = tid & 63;
    const int wave = tid >> 6;     // 0..7
    const int quad = lane >> 4;
    const int l16  = lane & 15;
    const int qt = blockIdx.x;     // 0..7 (256-row q-tiles)
    const int bh = blockIdx.y;     // 0..31
    const int b = bh >> 4, h = bh & 15;

    // ---- Q fragments: direct global -> registers (A-frag rows 16B-contiguous) ----
    bf16x8 qf[2][4];
    {
        const bf16_t* qg = Qw + ((size_t)(b * S_ + qt * 256 + wave * 32)) * HID + h * HD;
        for (int mt = 0; mt < 2; ++mt)
            for (int kk = 0; kk < 4; ++kk)
                qf[mt][kk] = *(const bf16x8*)(qg + (size_t)(mt * 16 + l16) * HID + kk * 32 + quad * 8);
    }

    f32x4 oa[2][8] = {};
    float mrow[2][4], lrow[2][4];
    for (int mt = 0; mt < 2; ++mt)
        for (int j = 0; j < 4; ++j) { mrow[mt][j] = -INFINITY; lrow[mt][j] = 0.f; }

    const float scale = 0.08838834764831845f;           // 1/sqrt(128)
    const float NEGF  = -3.4028234663852886e38f;

    const bf16_t* kg = Kc + (size_t)b * S_ * HD;
    const bf16_t* vg = Vt + (size_t)b * HD * S_;

    for (int kt = 0; kt < S_ / 64; ++kt) {
        __syncthreads();   // prev iter's sP(pf)/sV(vf) reads done before restaging
        for (int i = 0; i < 2; ++i) {
            int c = tid + i * 512;                       // 0..1023
            int kr = c >> 4, kc = (c & 15) * 8;          // sK: [64][128] stride 136
            *(uint4*)(&smem[kr * 136 + kc]) =
                *(const uint4*)(kg + (size_t)(kt * 64 + kr) * HD + kc);
            int vr = c >> 3, vc = (c & 7) * 8;           // sV = V^T: [128][64] stride 72
            *(uint4*)(&smem[SV_U + vr * 72 + vc]) =
                *(const uint4*)(vg + (size_t)vr * S_ + kt * 64 + vc);
        }
        if (tid < 64) {
            float mv = mask[b * S_ + kt * 64 + tid];
            sMask[tid] = (1.0f - mv) * NEGF;
        }
        __syncthreads();

        // ---- S = (Q K^T) * scale + maskadd ----
        f32x4 sa[2][4];
        for (int nt = 0; nt < 4; ++nt) {
            bf16x8 kf[4];
            for (int kk = 0; kk < 4; ++kk)
                kf[kk] = *(const bf16x8*)(&smem[(nt * 16 + l16) * 136 + kk * 32 + quad * 8]);
            for (int mt = 0; mt < 2; ++mt) {
                f32x4 a = {};
                for (int kk = 0; kk < 4; ++kk)
                    a = mfma16(qf[mt][kk], kf[kk], a);
                sa[mt][nt] = a;
            }
        }
        for (int mt = 0; mt < 2; ++mt)
            for (int nt = 0; nt < 4; ++nt) {
                float madd = sMask[nt * 16 + l16];
                for (int j = 0; j < 4; ++j)
                    sa[mt][nt][j] = sa[mt][nt][j] * scale + madd;
            }
        __syncthreads();   // all kf reads done before sP overlays sK region

        // ---- online softmax; P -> sP (wave-private rows) ----
        for (int mt = 0; mt < 2; ++mt) {
            float rm[4];
            for (int j = 0; j < 4; ++j) {
                float m = sa[mt][0][j];
                for (int nt = 1; nt < 4; ++nt) m = fmaxf(m, sa[mt][nt][j]);
                rm[j] = m;
            }
            for (int off = 1; off < 16; off <<= 1)
                for (int j = 0; j < 4; ++j)
                    rm[j] = fmaxf(rm[j], __shfl_xor(rm[j], off));
            float alpha[4];
            for (int j = 0; j < 4; ++j) {
                float mnew = fmaxf(mrow[mt][j], rm[j]);
                alpha[j] = __expf(mrow[mt][j] - mnew);
                mrow[mt][j] = mnew;
                lrow[mt][j] *= alpha[j];
                for (int nt = 0; nt < 8; ++nt) oa[mt][nt][j] *= alpha[j];
            }
            float rs[4] = {0.f, 0.f, 0.f, 0.f};
            bf16_t* sPp = (bf16_t*)&smem[wave * 2304];
            for (int nt = 0; nt < 4; ++nt)
                for (int j = 0; j < 4; ++j) {
                    float p = __expf(sa[mt][nt][j] - mrow[mt][j]);
                    rs[j] += p;
                    sPp[(mt * 16 + quad * 4 + j) * 72 + nt * 16 + l16] = (bf16_t)p;
                }
            for (int off = 1; off < 16; off <<= 1)
                for (int j = 0; j < 4; ++j) rs[j] += __shfl_xor(rs[j], off);
            for (int j = 0; j < 4; ++j) lrow[mt][j] += rs[j];
        }

        // ---- O += P V  (pf: wave-private sP rows; same-wave write->read) ----
        bf16x8 pf[2][2];
        for (int mt = 0; mt < 2; ++mt)
            for (int kk = 0; kk < 2; ++kk)
                pf[mt][kk] = *(const bf16x8*)(&smem[wave * 2304 + (mt * 16 + l16) * 72 + kk * 32 + quad * 8]);
        for (int nt = 0; nt < 8; ++nt)
            for (int kk = 0; kk < 2; ++kk) {
                bf16x8 vf = *(const bf16x8*)(&smem[SV_U + (nt * 16 + l16) * 72 + kk * 32 + quad * 8]);
                for (int mt = 0; mt < 2; ++mt)
                    oa[mt][nt] = mfma16(pf[mt][kk], vf, oa[mt][nt]);
            }
    }

    // ---- epilogue: O /= l, write [b,s,h*128+d] ----
    for (int mt = 0; mt < 2; ++mt)
        for (int j = 0; j < 4; ++j) {
            float inv = 1.0f / lrow[mt][j];
            int s = qt * 256 + wave * 32 + mt * 16 + quad * 4 + j;
            for (int nt = 0; nt < 8; ++nt) {
                int d = nt * 16 + l16;
                Ow[((size_t)(b * S_ + s)) * HID + h * HD + d] = (bf16_t)(oa[mt][nt][j] * inv);
            }
        }
}

// ---------------------------------------------------------------------------
// Scratch overlay inside d_out (all regions phase-disjoint):
//   O1 = out[0 : 8388608)          : wqb/wkb/wvb bf16 -> final out (gemm1)
//   O2 = out[8388608 : 16777216)   : qb bf16 | wob bf16 -> final key (bcast)
//   O3 = out[16777216 : 25165824)  : hsb bf16, then o_ws (alias) -> final value (bcast)
// d_ws: k_ws/v_ws/vt_ws bf16 = 3 MB only.
// Order: convert -> gemm0 -> attn -> gemm1 -> broadcast_kv (last).
// ---------------------------------------------------------------------------
extern "C" void kernel_launch(void* const* d_in, const int* in_sizes, int n_in,
                              void* d_out, int out_size, void* d_ws, size_t ws_size,
                              hipStream_t stream) {
    const float* hs   = (const float*)d_in[0];
    const float* mask = (const float*)d_in[1];
    const float* Wq   = (const float*)d_in[2];
    const float* Wk   = (const float*)d_in[3];
    const float* Wv   = (const float*)d_in[4];
    const float* Wo   = (const float*)d_in[5];
    float* out = (float*)d_out;

    bf16_t* wqb = (bf16_t*)out;                         // O1
    bf16_t* wkb = wqb + 4194304;
    bf16_t* wvb = wkb + 262144;
    bf16_t* qb  = (bf16_t*)(out + 8388608);             // O2
    bf16_t* wob = (bf16_t*)(out + 12582912);            // O2 tail
    bf16_t* hsb = (bf16_t*)(out + 16777216);            // O3
    bf16_t* o_ws = hsb;                                 // alias (hsb dead after gemm0)

    bf16_t* k_ws  = (bf16_t*)d_ws;                      // 524,288 bf16
    bf16_t* v_ws  = k_ws + 524288;
    bf16_t* vt_ws = v_ws + 524288;                      // total 3 MB

    // 1) fp32 -> bf16 staging
    convert_bf16<<<2048, 256, 0, stream>>>(hs, Wq, Wk, Wv, Wo, hsb, wqb, wkb, wvb, wob);
    // 2) QKV projection: Q->qb (O2), K->k_ws, V->v_ws + vt_ws
    gemm_nt<0><<<dim3(18, 32), 256, 0, stream>>>(hsb, wqb, wkb, wvb, qb, k_ws, v_ws, vt_ws, nullptr);
    // 3) flash MQA attention -> o_ws (O3, overwrites dead hsb)
    attn_kernel<<<dim3(8, 32), 512, 0, stream>>>(qb, k_ws, vt_ws, mask, o_ws);
    // 4) output projection -> fp32 out (O1, overwrites dead wq/wk/wv)
    gemm_nt<1><<<dim3(16, 32), 256, 0, stream>>>(o_ws, wob, nullptr, nullptr, nullptr, nullptr, nullptr, nullptr, out);
    // 5) key/value broadcast -> O2/O3 (overwrites dead qb/wob/o_ws)
    broadcast_kv<<<4096, 256, 0, stream>>>(k_ws, v_ws, out + 8388608, out + 16777216);
}